// Round 7
// baseline (98.996 us; speedup 1.0000x reference)
//
#include <hip/hip_runtime.h>

typedef __attribute__((ext_vector_type(8))) short bf16x8;
typedef __attribute__((ext_vector_type(4))) float f32x4;

__device__ __forceinline__ ushort f32_to_bf16(float f) {
    union { float f; unsigned u; } v; v.f = f;
    unsigned b = v.u + 0x7FFF + ((v.u >> 16) & 1);
    return (ushort)(b >> 16);
}
__device__ __forceinline__ float bf16_to_f32(ushort h) {
    union { unsigned u; float f; } v; v.u = ((unsigned)h) << 16;
    return v.f;
}
__device__ __forceinline__ void split2(float x, ushort& a, ushort& b) {
    a = f32_to_bf16(x); float r1 = x - bf16_to_f32(a);
    b = f32_to_bf16(r1);
}

__device__ __forceinline__ void vmwait4() { asm volatile("s_waitcnt vmcnt(4)" ::: "memory"); }
__device__ __forceinline__ void vmwait0() { asm volatile("s_waitcnt vmcnt(0)" ::: "memory"); }
__device__ __forceinline__ void lgwait0() { asm volatile("s_waitcnt lgkmcnt(0)" ::: "memory"); }
__device__ __forceinline__ void blockbar() {
    __builtin_amdgcn_sched_barrier(0);
    __builtin_amdgcn_s_barrier();
    __builtin_amdgcn_sched_barrier(0);
}

// 64 rows x 128B tile global->LDS, XOR swizzle via global source (rule #21), t256 in [0,256)
__device__ __forceinline__ void stage64x64(const ushort* gsrc, int row_stride_elems,
                                           char* lds, int t256) {
    const char* gb = (const char*)gsrc;
    const int rs = row_stride_elems * 2;
#pragma unroll
    for (int j = 0; j < 2; ++j) {
        int o = (j * 256 + t256) * 16;
        int row = o >> 7;
        int col = (o & 127) ^ ((row & 7) << 4);
        __builtin_amdgcn_global_load_lds(
            (const __attribute__((address_space(1))) unsigned int*)(gb + row * rs + col),
            (__attribute__((address_space(3))) unsigned int*)(lds + o), 16, 0, 0);
    }
}
// 32 rows x 128B = 4KB, one pass with 256 threads
__device__ __forceinline__ void stage32x64(const ushort* gsrc, int row_stride_elems,
                                           char* lds, int t) {
    const char* gb = (const char*)gsrc;
    const int rs = row_stride_elems * 2;
    int o = t * 16;
    int row = o >> 7;
    int col = (o & 127) ^ ((row & 7) << 4);
    __builtin_amdgcn_global_load_lds(
        (const __attribute__((address_space(1))) unsigned int*)(gb + row * rs + col),
        (__attribute__((address_space(3))) unsigned int*)(lds + o), 16, 0, 0);
}

__device__ __forceinline__ bf16x8 fragld(const char* lds, int row, int kbyte) {
    return *(const bf16x8*)(lds + (row << 7) + (kbyte ^ ((row & 7) << 4)));
}

// =================== prep_all: XT split + conv_ws + conv_wa (slimmed) ===================
__global__ __launch_bounds__(256) void prep_all(const float* __restrict__ X,
        ushort* __restrict__ XT1, ushort* __restrict__ XT2,
        const float* __restrict__ Ws, ushort* __restrict__ Ws16,
        const float* __restrict__ Wa, ushort* __restrict__ Wa1, ushort* __restrict__ Wa2) {
    __shared__ float tile[64][68];
    const int bx = blockIdx.x;
    const int t = threadIdx.x;
    if (bx < 256) {                       // ---- X -> XT1/XT2 (transposed split2) ----
        const int b = bx >> 5, n0 = (bx & 31) * 64;
#pragma unroll
        for (int it = 0; it < 4; ++it) {
            int f = it * 256 + t, r = f >> 4, q = (f & 15) * 4;
            float4 v = *(const float4*)&X[((size_t)b * 2048 + n0 + r) * 64 + q];
            tile[r][q + 0] = v.x; tile[r][q + 1] = v.y; tile[r][q + 2] = v.z; tile[r][q + 3] = v.w;
        }
        __syncthreads();
#pragma unroll
        for (int it = 0; it < 4; ++it) {  // T-layout: row = b*64+c, cols n
            int f = it * 256 + t, c = f >> 4, q = (f & 15) * 4;
            ushort4 h1, h2;
            split2(tile[q + 0][c], h1.x, h2.x); split2(tile[q + 1][c], h1.y, h2.y);
            split2(tile[q + 2][c], h1.z, h2.z); split2(tile[q + 3][c], h1.w, h2.w);
            size_t a = (size_t)(b * 64 + c) * 2048 + n0 + q;
            *(ushort4*)&XT1[a] = h1; *(ushort4*)&XT2[a] = h2;
        }
    } else if (bx < 2304) {               // ---- conv_ws ----
        size_t idx = ((size_t)(bx - 256) * 256 + t) * 8;
#pragma unroll
        for (int h = 0; h < 2; ++h) {
            float4 v = *(const float4*)&Ws[idx + h * 4];
            ushort4 a;
            a.x = f32_to_bf16(v.x); a.y = f32_to_bf16(v.y);
            a.z = f32_to_bf16(v.z); a.w = f32_to_bf16(v.w);
            *(ushort4*)&Ws16[idx + h * 4] = a;
        }
    } else {                              // ---- conv_wa split2 ----
        size_t idx = ((size_t)(bx - 2304) * 256 + t) * 8;
#pragma unroll
        for (int h = 0; h < 2; ++h) {
            float4 v = *(const float4*)&Wa[idx + h * 4];
            ushort4 a, b;
            split2(v.x, a.x, b.x); split2(v.y, a.y, b.y);
            split2(v.z, a.z, b.z); split2(v.w, a.w, b.w);
            *(ushort4*)&Wa1[idx + h * 4] = a; *(ushort4*)&Wa2[idx + h * 4] = b;
        }
    }
}

// =================== xo body: X -> X1o/X2o (orig layout split2) + ThsT ===================
__device__ __forceinline__ void xo_body(int idx, const float* __restrict__ X,
        ushort* __restrict__ X1o, ushort* __restrict__ X2o,
        const float* __restrict__ Ths, ushort* __restrict__ ThsT) {
    const int t = threadIdx.x;
    {
        size_t e = ((size_t)idx * 512 + t) * 8;
        int c0 = (int)(e & 63);
        int n  = (int)((e >> 6) & 2047);
        int b  = (int)(e >> 17);
        float4 v0 = *(const float4*)&X[e];
        float4 v1 = *(const float4*)&X[e + 4];
        uint4 w1, w2;
        ushort* u1 = (ushort*)&w1; ushort* u2 = (ushort*)&w2;
        split2(v0.x, u1[0], u2[0]); split2(v0.y, u1[1], u2[1]);
        split2(v0.z, u1[2], u2[2]); split2(v0.w, u1[3], u2[3]);
        split2(v1.x, u1[4], u2[4]); split2(v1.y, u1[5], u2[5]);
        split2(v1.z, u1[6], u2[6]); split2(v1.w, u1[7], u2[7]);
        size_t dst = (size_t)n * 512 + b * 64 + c0;
        *(uint4*)&X1o[dst] = w1;
        *(uint4*)&X2o[dst] = w2;
    }
    if (idx < 8) {
#pragma unroll
        for (int k = 0; k < 4; ++k) {
            int idx2 = idx * 512 + t + k * 4096;   // k*4096 + o*64 + i
            int kk = idx2 >> 12, o = (idx2 >> 6) & 63, i = idx2 & 63;
            ThsT[idx2] = f32_to_bf16(Ths[kk * 4096 + i * 64 + o]);
        }
    }
}

// =================== gemm_s body: 2-phase dbuf pipeline, in-block K-split ===================
template <int MODE>
__device__ __forceinline__ void gemm_s_body(int bx, const ushort* __restrict__ A,
        const ushort* __restrict__ BT, const ushort* __restrict__ CinT,
        ushort* __restrict__ YT, ushort* __restrict__ Yo, char* ls) {
    const int t = threadIdx.x;
    const int g = t >> 8, t256 = t & 255;
    const int m0 = (bx & 31) * 64, c0 = (bx >> 5) * 64;
    const int lane = t & 63;
    const int wg = (t >> 6) & 3, wr = wg >> 1, wc = wg & 1;
    const int l15 = lane & 15, l4 = lane >> 4;
    char* base = ls + g * 32768;
    const ushort* Ap = A + (size_t)m0 * 2048 + (size_t)g * 1024;
    const ushort* Bp = BT + (size_t)c0 * 2048 + (size_t)g * 1024;

    f32x4 z = {0.f, 0.f, 0.f, 0.f};
    f32x4 acc[2][2];
    acc[0][0] = z; acc[0][1] = z; acc[1][0] = z; acc[1][1] = z;

    stage64x64(Ap, 2048, base, t256);
    stage64x64(Bp, 2048, base + 8192, t256);
    for (int ts = 0; ts < 16; ++ts) {
        char* cur = base + (ts & 1) * 16384;
        if (ts < 15) {
            char* nxt = base + ((ts + 1) & 1) * 16384;
            stage64x64(Ap + (ts + 1) * 64, 2048, nxt, t256);
            stage64x64(Bp + (ts + 1) * 64, 2048, nxt + 8192, t256);
            vmwait4();
        } else {
            vmwait0();
        }
        blockbar();
#pragma unroll
        for (int s = 0; s < 2; ++s) {
            const int kb = s * 64 + l4 * 16;
            bf16x8 aF[2], bF[2];
#pragma unroll
            for (int f = 0; f < 2; ++f) {
                aF[f] = fragld(cur, wr * 32 + f * 16 + l15, kb);
                bF[f] = fragld(cur + 8192, wc * 32 + f * 16 + l15, kb);
            }
#pragma unroll
            for (int i = 0; i < 2; ++i)
#pragma unroll
                for (int j = 0; j < 2; ++j)
                    acc[i][j] = __builtin_amdgcn_mfma_f32_16x16x32_bf16(aF[i], bF[j], acc[i][j], 0, 0, 0);
        }
        lgwait0();
        blockbar();
    }

    float* red = (float*)ls;
    ushort* tileo = (ushort*)(ls + 17408);
    if (g == 0) {
#pragma unroll
        for (int i = 0; i < 2; ++i)
#pragma unroll
            for (int j = 0; j < 2; ++j) {
                const int lrb = wr * 32 + i * 16 + l4 * 4;
                const int lc = wc * 32 + j * 16 + l15;
#pragma unroll
                for (int r = 0; r < 4; ++r) red[(lrb + r) * 65 + lc] = acc[i][j][r];
            }
    }
    __syncthreads();
    if (g == 1) {
#pragma unroll
        for (int i = 0; i < 2; ++i)
#pragma unroll
            for (int j = 0; j < 2; ++j) {
                const int lrb = wr * 32 + i * 16 + l4 * 4;
                const int lc = wc * 32 + j * 16 + l15;
                float vv[4];
#pragma unroll
                for (int r = 0; r < 4; ++r) vv[r] = red[(lrb + r) * 65 + lc] + acc[i][j][r];
                if (MODE == 1) {
                    ushort4 ci = *(const ushort4*)&CinT[(size_t)(c0 + lc) * 2048 + m0 + lrb];
                    vv[0] = 2.f * vv[0] - bf16_to_f32(ci.x);
                    vv[1] = 2.f * vv[1] - bf16_to_f32(ci.y);
                    vv[2] = 2.f * vv[2] - bf16_to_f32(ci.z);
                    vv[3] = 2.f * vv[3] - bf16_to_f32(ci.w);
                }
                ushort4 p;
                p.x = f32_to_bf16(vv[0]); p.y = f32_to_bf16(vv[1]);
                p.z = f32_to_bf16(vv[2]); p.w = f32_to_bf16(vv[3]);
                *(ushort4*)&YT[(size_t)(c0 + lc) * 2048 + m0 + lrb] = p;
                tileo[(lrb + 0) * 64 + lc] = p.x;
                tileo[(lrb + 1) * 64 + lc] = p.y;
                tileo[(lrb + 2) * 64 + lc] = p.z;
                tileo[(lrb + 3) * 64 + lc] = p.w;
            }
    }
    __syncthreads();
    {
        int row = t >> 3, ch = t & 7;
        *(uint4*)&Yo[(size_t)(m0 + row) * 512 + c0 + ch * 8] = *(uint4*)&tileo[row * 64 + ch * 8];
    }
}

// =================== y3 body: split-K-2 across block pairs -> f32 partials P0/P1 ===================
__device__ __forceinline__ void y3_body(int bx, const ushort* __restrict__ A,
        const ushort* __restrict__ BT, float* __restrict__ P0, float* __restrict__ P1,
        char* ls) {
    const int t = threadIdx.x;
    const int g = t >> 8, t256 = t & 255;
    const int tile = bx >> 1, g2 = bx & 1;
    const int m0 = (tile & 31) * 64, c0 = (tile >> 5) * 64;
    const int lane = t & 63;
    const int wg = (t >> 6) & 3, wr = wg >> 1, wc = wg & 1;
    const int l15 = lane & 15, l4 = lane >> 4;
    char* base = ls + g * 32768;
    const size_t kbase = (size_t)g2 * 1024 + (size_t)g * 512;
    const ushort* Ap = A + (size_t)m0 * 2048 + kbase;
    const ushort* Bp = BT + (size_t)c0 * 2048 + kbase;

    f32x4 z = {0.f, 0.f, 0.f, 0.f};
    f32x4 acc[2][2];
    acc[0][0] = z; acc[0][1] = z; acc[1][0] = z; acc[1][1] = z;

    stage64x64(Ap, 2048, base, t256);
    stage64x64(Bp, 2048, base + 8192, t256);
    for (int ts = 0; ts < 8; ++ts) {
        char* cur = base + (ts & 1) * 16384;
        if (ts < 7) {
            char* nxt = base + ((ts + 1) & 1) * 16384;
            stage64x64(Ap + (ts + 1) * 64, 2048, nxt, t256);
            stage64x64(Bp + (ts + 1) * 64, 2048, nxt + 8192, t256);
            vmwait4();
        } else {
            vmwait0();
        }
        blockbar();
#pragma unroll
        for (int s = 0; s < 2; ++s) {
            const int kb = s * 64 + l4 * 16;
            bf16x8 aF[2], bF[2];
#pragma unroll
            for (int f = 0; f < 2; ++f) {
                aF[f] = fragld(cur, wr * 32 + f * 16 + l15, kb);
                bF[f] = fragld(cur + 8192, wc * 32 + f * 16 + l15, kb);
            }
#pragma unroll
            for (int i = 0; i < 2; ++i)
#pragma unroll
                for (int j = 0; j < 2; ++j)
                    acc[i][j] = __builtin_amdgcn_mfma_f32_16x16x32_bf16(aF[i], bF[j], acc[i][j], 0, 0, 0);
        }
        lgwait0();
        blockbar();
    }

    float* red = (float*)ls;
    float* tf = (float*)(ls + 17408);
    if (g == 0) {
#pragma unroll
        for (int i = 0; i < 2; ++i)
#pragma unroll
            for (int j = 0; j < 2; ++j) {
                const int lrb = wr * 32 + i * 16 + l4 * 4;
                const int lc = wc * 32 + j * 16 + l15;
#pragma unroll
                for (int r = 0; r < 4; ++r) red[(lrb + r) * 65 + lc] = acc[i][j][r];
            }
    }
    __syncthreads();
    if (g == 1) {
#pragma unroll
        for (int i = 0; i < 2; ++i)
#pragma unroll
            for (int j = 0; j < 2; ++j) {
                const int lrb = wr * 32 + i * 16 + l4 * 4;
                const int lc = wc * 32 + j * 16 + l15;
#pragma unroll
                for (int r = 0; r < 4; ++r) tf[(lrb + r) * 64 + lc] = red[(lrb + r) * 65 + lc] + acc[i][j][r];
            }
    }
    __syncthreads();
    {
        float* Pd = g2 ? P1 : P0;
        int row = t >> 3, q = (t & 7) * 8;
        *(float4*)&Pd[(size_t)(m0 + row) * 512 + c0 + q]     = *(float4*)&tf[row * 64 + q];
        *(float4*)&Pd[(size_t)(m0 + row) * 512 + c0 + q + 4] = *(float4*)&tf[row * 64 + q + 4];
    }
}

// =================== gemm3 body: WaX split-2 (3 products), split-K-2 across blocks ===================
__device__ __forceinline__ void gemm3_body(int bxx, const ushort* __restrict__ A1,
        const ushort* __restrict__ A2, const ushort* __restrict__ B1,
        const ushort* __restrict__ B2, float* __restrict__ WaXP0,
        float* __restrict__ WaXP1, char* ls) {
    const int t = threadIdx.x;
    const int g = t >> 8, t256 = t & 255;
    const int tile = bxx >> 1, g2 = bxx & 1;
    const int m0 = (tile & 31) * 64, c0 = (tile >> 5) * 64;
    const int lane = t & 63;
    const int wg = (t >> 6) & 3, wr = wg >> 1, wc = wg & 1;
    const int l15 = lane & 15, l4 = lane >> 4;
    char* base = ls + g * 32768;
    const size_t kbase = (size_t)g2 * 1024 + (size_t)g * 512;

    f32x4 z = {0.f, 0.f, 0.f, 0.f};
    f32x4 acc[2][2];
    acc[0][0] = z; acc[0][1] = z; acc[1][0] = z; acc[1][1] = z;

    for (int k0 = 0; k0 < 512; k0 += 64) {
        stage64x64(A1 + (size_t)m0 * 2048 + kbase + k0, 2048, base + 0 * 8192, t256);
        stage64x64(A2 + (size_t)m0 * 2048 + kbase + k0, 2048, base + 1 * 8192, t256);
        stage64x64(B1 + (size_t)c0 * 2048 + kbase + k0, 2048, base + 2 * 8192, t256);
        stage64x64(B2 + (size_t)c0 * 2048 + kbase + k0, 2048, base + 3 * 8192, t256);
        __syncthreads();
#pragma unroll
        for (int s = 0; s < 2; ++s) {
            const int kb = s * 64 + l4 * 16;
            bf16x8 a1F[2], a2F[2], b1F[2], b2F[2];
#pragma unroll
            for (int f = 0; f < 2; ++f) {
                const int ar = wr * 32 + f * 16 + l15;
                const int br = wc * 32 + f * 16 + l15;
                a1F[f] = fragld(base + 0 * 8192, ar, kb);
                a2F[f] = fragld(base + 1 * 8192, ar, kb);
                b1F[f] = fragld(base + 2 * 8192, br, kb);
                b2F[f] = fragld(base + 3 * 8192, br, kb);
            }
#pragma unroll
            for (int i = 0; i < 2; ++i)
#pragma unroll
                for (int j = 0; j < 2; ++j) {
                    f32x4 a = acc[i][j];
                    a = __builtin_amdgcn_mfma_f32_16x16x32_bf16(a1F[i], b1F[j], a, 0, 0, 0);
                    a = __builtin_amdgcn_mfma_f32_16x16x32_bf16(a1F[i], b2F[j], a, 0, 0, 0);
                    a = __builtin_amdgcn_mfma_f32_16x16x32_bf16(a2F[i], b1F[j], a, 0, 0, 0);
                    acc[i][j] = a;
                }
        }
        __syncthreads();
    }

    float* red = (float*)ls;
    if (g == 0) {
#pragma unroll
        for (int i = 0; i < 2; ++i)
#pragma unroll
            for (int j = 0; j < 2; ++j) {
                const int lrb = wr * 32 + i * 16 + l4 * 4;
                const int lc = wc * 32 + j * 16 + l15;
#pragma unroll
                for (int r = 0; r < 4; ++r) red[(lrb + r) * 65 + lc] = acc[i][j][r];
            }
    }
    __syncthreads();
    if (g == 1) {
        float* Wd = g2 ? WaXP1 : WaXP0;
#pragma unroll
        for (int i = 0; i < 2; ++i)
#pragma unroll
            for (int j = 0; j < 2; ++j) {
                const int lrb = wr * 32 + i * 16 + l4 * 4;
                const int lc = wc * 32 + j * 16 + l15;
                f32x4 v;
#pragma unroll
                for (int r = 0; r < 4; ++r) v[r] = red[(lrb + r) * 65 + lc] + acc[i][j][r];
                *(f32x4*)&Wd[(size_t)(c0 + lc) * 2048 + m0 + lrb] = v;
            }
    }
}

// =================== gram body: 256 work items (8 b x 32 chunks of 64 n), 512 thr ===================
__device__ __forceinline__ void gram_body(int idx, const float* __restrict__ WaXP0,
        const float* __restrict__ WaXP1,
        const ushort* __restrict__ XT1, const ushort* __restrict__ XT2,
        float* __restrict__ Gpart, char* lsraw) {
    const int b = idx & 7, chunk = idx >> 3;
    float (*Lw)[68] = (float(*)[68])lsraw;
    float (*Rx)[68] = (float(*)[68])(lsraw + 64 * 68 * 4);
    const int t = threadIdx.x;
    const int n0 = chunk * 64;
    {
        const int r = t >> 3, q = (t & 7) * 8;
        size_t a = (size_t)(b * 64 + r) * 2048 + n0 + q;
        float4 w0a = *(const float4*)&WaXP0[a];
        float4 w0b = *(const float4*)&WaXP0[a + 4];
        float4 w1a = *(const float4*)&WaXP1[a];
        float4 w1b = *(const float4*)&WaXP1[a + 4];
        Lw[r][q + 0] = w0a.x + w1a.x; Lw[r][q + 1] = w0a.y + w1a.y;
        Lw[r][q + 2] = w0a.z + w1a.z; Lw[r][q + 3] = w0a.w + w1a.w;
        Lw[r][q + 4] = w0b.x + w1b.x; Lw[r][q + 5] = w0b.y + w1b.y;
        Lw[r][q + 6] = w0b.z + w1b.z; Lw[r][q + 7] = w0b.w + w1b.w;
#pragma unroll
        for (int h = 0; h < 2; ++h) {
            ushort4 h1 = *(const ushort4*)&XT1[a + h * 4];
            ushort4 h2 = *(const ushort4*)&XT2[a + h * 4];
            Rx[r][q + h * 4 + 0] = bf16_to_f32(h1.x) + bf16_to_f32(h2.x);
            Rx[r][q + h * 4 + 1] = bf16_to_f32(h1.y) + bf16_to_f32(h2.y);
            Rx[r][q + h * 4 + 2] = bf16_to_f32(h1.z) + bf16_to_f32(h2.z);
            Rx[r][q + h * 4 + 3] = bf16_to_f32(h1.w) + bf16_to_f32(h2.w);
        }
    }
    __syncthreads();
    if (t < 256) {
        const int tx = t & 15, ty = t >> 4;
        float acc[4][4] = {{0.f,0.f,0.f,0.f},{0.f,0.f,0.f,0.f},{0.f,0.f,0.f,0.f},{0.f,0.f,0.f,0.f}};
        for (int n = 0; n < 64; ++n) {
            float a[4], bb[4];
#pragma unroll
            for (int i = 0; i < 4; ++i) { a[i] = Lw[ty * 4 + i][n]; bb[i] = Rx[tx * 4 + i][n]; }
#pragma unroll
            for (int i = 0; i < 4; ++i)
#pragma unroll
                for (int j = 0; j < 4; ++j) acc[i][j] = fmaf(a[i], bb[j], acc[i][j]);
        }
        float* gp = Gpart + (size_t)(chunk * 8 + b) * 4096;
#pragma unroll
        for (int i = 0; i < 4; ++i)
            *(float4*)&gp[(ty * 4 + i) * 64 + tx * 4] =
                make_float4(acc[i][0], acc[i][1], acc[i][2], acc[i][3]);
    }
}

// =================== cheb body: per-batch Chebyshev, all 512 threads (2x4 microtile) ===================
__device__ __forceinline__ void cheb_body(int b, const float* __restrict__ Gpart,
        const float* __restrict__ Thd, ushort* __restrict__ DT1, ushort* __restrict__ DT2,
        char* lsraw) {
    float (*Gs)[68]  = (float(*)[68])lsraw;
    float (*C2s)[68] = (float(*)[68])(lsraw + 17408);
    float (*C3s)[68] = (float(*)[68])(lsraw + 34816);
    const int t = threadIdx.x;
    for (int i = t; i < 4096; i += 512) {
        float s = 0.f;
#pragma unroll
        for (int c = 0; c < 32; ++c) s += Gpart[((size_t)c * 8 + b) * 4096 + i];
        Gs[i >> 6][i & 63] = s;
    }
    __syncthreads();
    const int tx = t & 15, ty = t >> 4;   // ty in [0,32)
    const int r0 = ty * 2, c0 = tx * 4;
    {   // C2 = 2*G@G - I
        float p[2][4] = {{0,0,0,0},{0,0,0,0}};
        for (int k = 0; k < 64; ++k) {
            float a0 = Gs[r0][k], a1 = Gs[r0 + 1][k];
            float4 bv = *(const float4*)&Gs[k][c0];
            p[0][0] = fmaf(a0, bv.x, p[0][0]); p[0][1] = fmaf(a0, bv.y, p[0][1]);
            p[0][2] = fmaf(a0, bv.z, p[0][2]); p[0][3] = fmaf(a0, bv.w, p[0][3]);
            p[1][0] = fmaf(a1, bv.x, p[1][0]); p[1][1] = fmaf(a1, bv.y, p[1][1]);
            p[1][2] = fmaf(a1, bv.z, p[1][2]); p[1][3] = fmaf(a1, bv.w, p[1][3]);
        }
#pragma unroll
        for (int i = 0; i < 2; ++i)
#pragma unroll
            for (int j = 0; j < 4; ++j)
                C2s[r0 + i][c0 + j] = 2.f * p[i][j] - ((r0 + i) == (c0 + j) ? 1.f : 0.f);
    }
    __syncthreads();
    {   // C3 = 2*G@C2 - G
        float q[2][4] = {{0,0,0,0},{0,0,0,0}};
        for (int k = 0; k < 64; ++k) {
            float a0 = Gs[r0][k], a1 = Gs[r0 + 1][k];
            float4 bv = *(const float4*)&C2s[k][c0];
            q[0][0] = fmaf(a0, bv.x, q[0][0]); q[0][1] = fmaf(a0, bv.y, q[0][1]);
            q[0][2] = fmaf(a0, bv.z, q[0][2]); q[0][3] = fmaf(a0, bv.w, q[0][3]);
            q[1][0] = fmaf(a1, bv.x, q[1][0]); q[1][1] = fmaf(a1, bv.y, q[1][1]);
            q[1][2] = fmaf(a1, bv.z, q[1][2]); q[1][3] = fmaf(a1, bv.w, q[1][3]);
        }
#pragma unroll
        for (int i = 0; i < 2; ++i)
#pragma unroll
            for (int j = 0; j < 4; ++j)
                C3s[r0 + i][c0 + j] = 2.f * q[i][j] - Gs[r0 + i][c0 + j];
    }
    __syncthreads();
    float d[2][4];
    {   // D = Thd0 + G@Thd1 + C2@Thd2 + C3@Thd3
#pragma unroll
        for (int i = 0; i < 2; ++i) {
            float4 t0 = *(const float4*)&Thd[(r0 + i) * 64 + c0];
            d[i][0] = t0.x; d[i][1] = t0.y; d[i][2] = t0.z; d[i][3] = t0.w;
        }
        for (int k = 0; k < 64; ++k) {
            float4 t1 = *(const float4*)&Thd[4096 + k * 64 + c0];
            float4 t2 = *(const float4*)&Thd[8192 + k * 64 + c0];
            float4 t3 = *(const float4*)&Thd[12288 + k * 64 + c0];
            float g0 = Gs[r0][k], g1 = Gs[r0 + 1][k];
            float c20 = C2s[r0][k], c21 = C2s[r0 + 1][k];
            float c30 = C3s[r0][k], c31 = C3s[r0 + 1][k];
            d[0][0] = fmaf(g0, t1.x, d[0][0]); d[0][1] = fmaf(g0, t1.y, d[0][1]);
            d[0][2] = fmaf(g0, t1.z, d[0][2]); d[0][3] = fmaf(g0, t1.w, d[0][3]);
            d[1][0] = fmaf(g1, t1.x, d[1][0]); d[1][1] = fmaf(g1, t1.y, d[1][1]);
            d[1][2] = fmaf(g1, t1.z, d[1][2]); d[1][3] = fmaf(g1, t1.w, d[1][3]);
            d[0][0] = fmaf(c20, t2.x, d[0][0]); d[0][1] = fmaf(c20, t2.y, d[0][1]);
            d[0][2] = fmaf(c20, t2.z, d[0][2]); d[0][3] = fmaf(c20, t2.w, d[0][3]);
            d[1][0] = fmaf(c21, t2.x, d[1][0]); d[1][1] = fmaf(c21, t2.y, d[1][1]);
            d[1][2] = fmaf(c21, t2.z, d[1][2]); d[1][3] = fmaf(c21, t2.w, d[1][3]);
            d[0][0] = fmaf(c30, t3.x, d[0][0]); d[0][1] = fmaf(c30, t3.y, d[0][1]);
            d[0][2] = fmaf(c30, t3.z, d[0][2]); d[0][3] = fmaf(c30, t3.w, d[0][3]);
            d[1][0] = fmaf(c31, t3.x, d[1][0]); d[1][1] = fmaf(c31, t3.y, d[1][1]);
            d[1][2] = fmaf(c31, t3.z, d[1][2]); d[1][3] = fmaf(c31, t3.w, d[1][3]);
        }
    }
    __syncthreads();
#pragma unroll
    for (int i = 0; i < 2; ++i)
#pragma unroll
        for (int j = 0; j < 4; ++j) Gs[r0 + i][c0 + j] = d[i][j];
    __syncthreads();
    for (int it = 0; it < 8; ++it) {
        int idx = it * 512 + t;              // o*64 + i (transposed emit)
        int o = idx >> 6, ii = idx & 63;
        ushort h1, h2;
        split2(Gs[ii][o], h1, h2);
        DT1[b * 4096 + idx] = h1;
        DT2[b * 4096 + idx] = h2;
    }
}

// =================== mega kernels ===================
__global__ __launch_bounds__(512, 4) void mega1(const ushort* __restrict__ Wa1,
        const ushort* __restrict__ Wa2, const ushort* __restrict__ XT1,
        const ushort* __restrict__ XT2, float* __restrict__ WaXP0, float* __restrict__ WaXP1,
        const ushort* __restrict__ Ws16, ushort* __restrict__ Y1T, ushort* __restrict__ Y1o,
        const float* __restrict__ X, ushort* __restrict__ X1o, ushort* __restrict__ X2o,
        const float* __restrict__ Ths, ushort* __restrict__ ThsT) {
    __shared__ __align__(16) char ls[65536];
    const int bx = blockIdx.x;
    const int role = bx & 3, idx = bx >> 2;
    if (role <= 1)      gemm3_body(idx * 2 + role, Wa1, Wa2, XT1, XT2, WaXP0, WaXP1, ls);
    else if (role == 2) gemm_s_body<0>(idx, Ws16, XT1, nullptr, Y1T, Y1o, ls);
    else                xo_body(idx, X, X1o, X2o, Ths, ThsT);
}

__global__ __launch_bounds__(512, 4) void mega2(const ushort* __restrict__ Ws16,
        const ushort* __restrict__ Y1T, const ushort* __restrict__ XT1,
        ushort* __restrict__ Y2T, ushort* __restrict__ Y2o,
        const float* __restrict__ WaXP0, const float* __restrict__ WaXP1,
        const ushort* __restrict__ XT2, float* __restrict__ Gpart) {
    __shared__ __align__(16) char ls[65536];
    const int bx = blockIdx.x;
    const int role = bx & 1, idx = bx >> 1;
    if (role == 0) gemm_s_body<1>(idx, Ws16, Y1T, XT1, Y2T, Y2o, ls);
    else           gram_body(idx, WaXP0, WaXP1, XT1, XT2, Gpart, ls);
}

__global__ __launch_bounds__(512, 4) void mega3(const ushort* __restrict__ Ws16,
        const ushort* __restrict__ Y2T, float* __restrict__ P0, float* __restrict__ P1,
        const float* __restrict__ Gpart, const float* __restrict__ Thd,
        ushort* __restrict__ DT1, ushort* __restrict__ DT2) {
    __shared__ __align__(16) char ls[65536];
    const int bx = blockIdx.x;
    if (bx < 8) cheb_body(bx, Gpart, Thd, DT1, DT2, ls);    // cheb FIRST: co-resident at t=0
    else        y3_body(bx - 8, Ws16, Y2T, P0, P1, ls);
}

// =================== fused epilogue: 512 blocks (n-tile 32), Y3 combine folded in ===================
__global__ __launch_bounds__(256) void ep_fused(const ushort* __restrict__ ThsT,
                                                const ushort* __restrict__ DT1, const ushort* __restrict__ DT2,
                                                const ushort* __restrict__ X1o, const ushort* __restrict__ X2o,
                                                const ushort* __restrict__ Y1o, const ushort* __restrict__ Y2o,
                                                const float* __restrict__ P0, const float* __restrict__ P1,
                                                float* __restrict__ out) {
    __shared__ __align__(16) char ls[49152];   // B slots 4x4KB @0..16K, A slots 4x8KB @16K..48K
    const int b = blockIdx.y, n0 = blockIdx.x * 32;
    const int t = threadIdx.x, lane = t & 63, w = t >> 6, wr = w & 1, wc = w >> 1;
    const int l15 = lane & 15, l4 = lane >> 4;

    // early reg loads for Y3 combine (8 elems/thread: row r3, cols q3..q3+7)
    const int r3 = t >> 3, q3 = (t & 7) * 8;
    const size_t a3 = (size_t)(n0 + r3) * 512 + b * 64 + q3;
    float4 p0a = *(const float4*)&P0[a3];
    float4 p0b = *(const float4*)&P0[a3 + 4];
    float4 p1a = *(const float4*)&P1[a3];
    float4 p1b = *(const float4*)&P1[a3 + 4];
    ushort4 y1a = *(const ushort4*)&Y1o[a3];
    ushort4 y1b = *(const ushort4*)&Y1o[a3 + 4];

    stage32x64(X1o + (size_t)n0 * 512 + b * 64, 512, ls + 0 * 4096, t);
    stage32x64(Y1o + (size_t)n0 * 512 + b * 64, 512, ls + 1 * 4096, t);
    stage32x64(Y2o + (size_t)n0 * 512 + b * 64, 512, ls + 2 * 4096, t);
    stage64x64(ThsT + 0 * 4096, 64, ls + 16384 + 0 * 8192, t);
    stage64x64(ThsT + 1 * 4096, 64, ls + 16384 + 1 * 8192, t);
    stage64x64(ThsT + 2 * 4096, 64, ls + 16384 + 2 * 8192, t);
    stage64x64(ThsT + 3 * 4096, 64, ls + 16384 + 3 * 8192, t);
    {   // slot 3: Y3 = 2*(P0+P1) - Y1 -> bf16, swizzled ds_write (one 16B word/thread)
        uint4 wv;
        ushort* u = (ushort*)&wv;
        u[0] = f32_to_bf16(2.f * (p0a.x + p1a.x) - bf16_to_f32(y1a.x));
        u[1] = f32_to_bf16(2.f * (p0a.y + p1a.y) - bf16_to_f32(y1a.y));
        u[2] = f32_to_bf16(2.f * (p0a.z + p1a.z) - bf16_to_f32(y1a.z));
        u[3] = f32_to_bf16(2.f * (p0a.w + p1a.w) - bf16_to_f32(y1a.w));
        u[4] = f32_to_bf16(2.f * (p0b.x + p1b.x) - bf16_to_f32(y1b.x));
        u[5] = f32_to_bf16(2.f * (p0b.y + p1b.y) - bf16_to_f32(y1b.y));
        u[6] = f32_to_bf16(2.f * (p0b.z + p1b.z) - bf16_to_f32(y1b.z));
        u[7] = f32_to_bf16(2.f * (p0b.w + p1b.w) - bf16_to_f32(y1b.w));
        *(uint4*)(ls + 3 * 4096 + (r3 << 7) + ((q3 * 2) ^ ((r3 & 7) << 4))) = wv;
    }
    __syncthreads();

    f32x4 z = {0.f, 0.f, 0.f, 0.f};
    f32x4 as[2], ad[2];
    as[0] = z; as[1] = z; ad[0] = z; ad[1] = z;
#pragma unroll
    for (int s = 0; s < 2; ++s) {
        const int kb = s * 64 + l4 * 16;
#pragma unroll
        for (int p = 0; p < 4; ++p) {
            bf16x8 bF = fragld(ls + p * 4096, wc * 16 + l15, kb);
#pragma unroll
            for (int i = 0; i < 2; ++i) {
                bf16x8 aF = fragld(ls + 16384 + p * 8192, wr * 32 + i * 16 + l15, kb);
                as[i] = __builtin_amdgcn_mfma_f32_16x16x32_bf16(aF, bF, as[i], 0, 0, 0);
            }
        }
    }
    __syncthreads();
    stage64x64(DT1 + b * 4096, 64, ls + 16384 + 0 * 8192, t);
    stage64x64(DT2 + b * 4096, 64, ls + 16384 + 1 * 8192, t);
    stage32x64(X2o + (size_t)n0 * 512 + b * 64, 512, ls + 3 * 4096, t);
    __syncthreads();
#pragma unroll
    for (int s = 0; s < 2; ++s) {
        const int kb = s * 64 + l4 * 16;
        bf16x8 b0 = fragld(ls + 0 * 4096, wc * 16 + l15, kb);
        bf16x8 b3 = fragld(ls + 3 * 4096, wc * 16 + l15, kb);
#pragma unroll
        for (int i = 0; i < 2; ++i) {
            bf16x8 a1 = fragld(ls + 16384 + 0 * 8192, wr * 32 + i * 16 + l15, kb);
            bf16x8 a2 = fragld(ls + 16384 + 1 * 8192, wr * 32 + i * 16 + l15, kb);
            f32x4 a = ad[i];
            a = __builtin_amdgcn_mfma_f32_16x16x32_bf16(a1, b0, a, 0, 0, 0);
            a = __builtin_amdgcn_mfma_f32_16x16x32_bf16(a1, b3, a, 0, 0, 0);
            a = __builtin_amdgcn_mfma_f32_16x16x32_bf16(a2, b0, a, 0, 0, 0);
            ad[i] = a;
        }
    }
#pragma unroll
    for (int i = 0; i < 2; ++i) {
        const int ob = wr * 32 + i * 16 + l4 * 4;
        const int nn = wc * 16 + l15;
        float4 o4;
        o4.x = fmaxf(as[i][0], 0.f) + fmaxf(ad[i][0], 0.f);
        o4.y = fmaxf(as[i][1], 0.f) + fmaxf(ad[i][1], 0.f);
        o4.z = fmaxf(as[i][2], 0.f) + fmaxf(ad[i][2], 0.f);
        o4.w = fmaxf(as[i][3], 0.f) + fmaxf(ad[i][3], 0.f);
        *(float4*)&out[((size_t)b * 2048 + n0 + nn) * 64 + ob] = o4;
    }
}

extern "C" void kernel_launch(void* const* d_in, const int* in_sizes, int n_in,
                              void* d_out, int out_size, void* d_ws, size_t ws_size,
                              hipStream_t stream) {
    (void)in_sizes; (void)n_in; (void)out_size;
    const float* X   = (const float*)d_in[0];
    const float* Ws  = (const float*)d_in[1];
    const float* Wa  = (const float*)d_in[2];
    const float* Ths = (const float*)d_in[3];
    const float* Thd = (const float*)d_in[4];

    char* p = (char*)d_ws;
    auto alloc = [&](size_t bytes) { char* r = p; p += (bytes + 255) & ~(size_t)255; return r; };
    ushort* XT1 = (ushort*)alloc(512ull * 2048 * 2);
    ushort* XT2 = (ushort*)alloc(512ull * 2048 * 2);
    ushort* X1o = (ushort*)alloc(2048ull * 512 * 2);
    ushort* X2o = (ushort*)alloc(2048ull * 512 * 2);
    ushort* Ws16 = (ushort*)alloc(2048ull * 2048 * 2);
    ushort* Wa1 = (ushort*)alloc(2048ull * 2048 * 2);
    ushort* Wa2 = (ushort*)alloc(2048ull * 2048 * 2);
    ushort* Y1T = (ushort*)alloc(512ull * 2048 * 2);
    ushort* Y2T = (ushort*)alloc(512ull * 2048 * 2);
    ushort* Y1o = (ushort*)alloc(2048ull * 512 * 2);
    ushort* Y2o = (ushort*)alloc(2048ull * 512 * 2);
    float*  P0  = (float*)alloc(2048ull * 512 * 4);
    float*  P1  = (float*)alloc(2048ull * 512 * 4);
    float*  WaXP0 = (float*)alloc(512ull * 2048 * 4);
    float*  WaXP1 = (float*)alloc(512ull * 2048 * 4);
    float*  Gpart = (float*)alloc(32ull * 8 * 4096 * 4);
    ushort* DT1 = (ushort*)alloc(8ull * 4096 * 2);
    ushort* DT2 = (ushort*)alloc(8ull * 4096 * 2);
    ushort* ThsT = (ushort*)alloc(4ull * 4096 * 2);
    if ((size_t)(p - (char*)d_ws) > ws_size) return;   // visible failure if ws too small

    prep_all<<<4352, 256, 0, stream>>>(X, XT1, XT2, Ws, Ws16, Wa, Wa1, Wa2);
    mega1<<<1024, 512, 0, stream>>>(Wa1, Wa2, XT1, XT2, WaXP0, WaXP1, Ws16, Y1T, Y1o,
                                    X, X1o, X2o, Ths, ThsT);
    mega2<<<512, 512, 0, stream>>>(Ws16, Y1T, XT1, Y2T, Y2o, WaXP0, WaXP1, XT2, Gpart);
    mega3<<<520, 512, 0, stream>>>(Ws16, Y2T, P0, P1, Gpart, Thd, DT1, DT2);
    ep_fused<<<dim3(64, 8), 256, 0, stream>>>(ThsT, DT1, DT2, X1o, X2o, Y1o, Y2o, P0, P1, (float*)d_out);
}

// Round 8
// 82.664 us; speedup vs baseline: 1.1976x; 1.1976x over previous
//
#include <hip/hip_runtime.h>

typedef __attribute__((ext_vector_type(8))) short bf16x8;
typedef __attribute__((ext_vector_type(4))) float f32x4;

__device__ __forceinline__ ushort f32_to_bf16(float f) {
    union { float f; unsigned u; } v; v.f = f;
    unsigned b = v.u + 0x7FFF + ((v.u >> 16) & 1);
    return (ushort)(b >> 16);
}
__device__ __forceinline__ float bf16_to_f32(ushort h) {
    union { unsigned u; float f; } v; v.u = ((unsigned)h) << 16;
    return v.f;
}
__device__ __forceinline__ void split2(float x, ushort& a, ushort& b) {
    a = f32_to_bf16(x); float r1 = x - bf16_to_f32(a);
    b = f32_to_bf16(r1);
}

__device__ __forceinline__ void vmwait4() { asm volatile("s_waitcnt vmcnt(4)" ::: "memory"); }
__device__ __forceinline__ void vmwait0() { asm volatile("s_waitcnt vmcnt(0)" ::: "memory"); }
__device__ __forceinline__ void lgwait0() { asm volatile("s_waitcnt lgkmcnt(0)" ::: "memory"); }
__device__ __forceinline__ void blockbar() {
    __builtin_amdgcn_sched_barrier(0);
    __builtin_amdgcn_s_barrier();
    __builtin_amdgcn_sched_barrier(0);
}

// 64 rows x 128B tile global->LDS, XOR swizzle via global source (rule #21), t256 in [0,256)
__device__ __forceinline__ void stage64x64(const ushort* gsrc, int row_stride_elems,
                                           char* lds, int t256) {
    const char* gb = (const char*)gsrc;
    const int rs = row_stride_elems * 2;
#pragma unroll
    for (int j = 0; j < 2; ++j) {
        int o = (j * 256 + t256) * 16;
        int row = o >> 7;
        int col = (o & 127) ^ ((row & 7) << 4);
        __builtin_amdgcn_global_load_lds(
            (const __attribute__((address_space(1))) unsigned int*)(gb + row * rs + col),
            (__attribute__((address_space(3))) unsigned int*)(lds + o), 16, 0, 0);
    }
}

__device__ __forceinline__ bf16x8 fragld(const char* lds, int row, int kbyte) {
    return *(const bf16x8*)(lds + (row << 7) + (kbyte ^ ((row & 7) << 4)));
}

// =================== prep_all: fused prep_xt / conv_ws / conv_wa / conv_tht ===================
__global__ __launch_bounds__(256) void prep_all(const float* __restrict__ X,
        ushort* __restrict__ XT1, ushort* __restrict__ XT2,
        ushort* __restrict__ X1o, ushort* __restrict__ X2o,
        const float* __restrict__ Ws, ushort* __restrict__ Ws16,
        const float* __restrict__ Wa, ushort* __restrict__ Wa1,
        const float* __restrict__ Ths, ushort* __restrict__ ThsT) {
    __shared__ float tile[64][68];
    const int bx = blockIdx.x;
    const int t = threadIdx.x;
    if (bx < 256) {                       // ---- prep_xt ----
        const int b = bx >> 5, n0 = (bx & 31) * 64;
#pragma unroll
        for (int it = 0; it < 4; ++it) {
            int f = it * 256 + t, r = f >> 4, q = (f & 15) * 4;
            float4 v = *(const float4*)&X[((size_t)b * 2048 + n0 + r) * 64 + q];
            tile[r][q + 0] = v.x; tile[r][q + 1] = v.y; tile[r][q + 2] = v.z; tile[r][q + 3] = v.w;
        }
        __syncthreads();
#pragma unroll
        for (int it = 0; it < 4; ++it) {  // T-layout: row = b*64+c, cols n
            int f = it * 256 + t, c = f >> 4, q = (f & 15) * 4;
            ushort4 h1, h2;
            split2(tile[q + 0][c], h1.x, h2.x); split2(tile[q + 1][c], h1.y, h2.y);
            split2(tile[q + 2][c], h1.z, h2.z); split2(tile[q + 3][c], h1.w, h2.w);
            size_t a = (size_t)(b * 64 + c) * 2048 + n0 + q;
            *(ushort4*)&XT1[a] = h1; *(ushort4*)&XT2[a] = h2;
        }
#pragma unroll
        for (int it = 0; it < 4; ++it) {  // orig layout: row n, cols bc
            int f = it * 256 + t, n = f >> 4, q = (f & 15) * 4;
            ushort4 h1, h2;
            split2(tile[n][q + 0], h1.x, h2.x); split2(tile[n][q + 1], h1.y, h2.y);
            split2(tile[n][q + 2], h1.z, h2.z); split2(tile[n][q + 3], h1.w, h2.w);
            size_t a = (size_t)(n0 + n) * 512 + b * 64 + q;
            *(ushort4*)&X1o[a] = h1; *(ushort4*)&X2o[a] = h2;
        }
    } else if (bx < 2304) {               // ---- conv_ws: 8 elems/thread ----
        size_t idx = ((size_t)(bx - 256) * 256 + t) * 8;
#pragma unroll
        for (int h = 0; h < 2; ++h) {
            float4 v = *(const float4*)&Ws[idx + h * 4];
            ushort4 a;
            a.x = f32_to_bf16(v.x); a.y = f32_to_bf16(v.y);
            a.z = f32_to_bf16(v.z); a.w = f32_to_bf16(v.w);
            *(ushort4*)&Ws16[idx + h * 4] = a;
        }
    } else if (bx < 4352) {               // ---- conv_wa: plain bf16 (no residual) ----
        size_t idx = ((size_t)(bx - 2304) * 256 + t) * 8;
#pragma unroll
        for (int h = 0; h < 2; ++h) {
            float4 v = *(const float4*)&Wa[idx + h * 4];
            ushort4 a;
            a.x = f32_to_bf16(v.x); a.y = f32_to_bf16(v.y);
            a.z = f32_to_bf16(v.z); a.w = f32_to_bf16(v.w);
            *(ushort4*)&Wa1[idx + h * 4] = a;
        }
    } else {                              // ---- conv_tht (transpose Theta_s) ----
        int idx = (bx - 4352) * 256 + t;  // k*4096 + o*64 + i
        int k = idx >> 12, o = (idx >> 6) & 63, i = idx & 63;
        ThsT[idx] = f32_to_bf16(Ths[k * 4096 + i * 64 + o]);
    }
}

// =================== gemm_s body: 2-phase dbuf pipeline, in-block K-split ===================
template <int MODE>
__device__ __forceinline__ void gemm_s_body(int bx, const ushort* __restrict__ A,
        const ushort* __restrict__ BT, const ushort* __restrict__ CinT,
        ushort* __restrict__ YT, ushort* __restrict__ Yo, char* ls) {
    const int t = threadIdx.x;
    const int g = t >> 8, t256 = t & 255;
    const int m0 = (bx & 31) * 64, c0 = (bx >> 5) * 64;
    const int lane = t & 63;
    const int wg = (t >> 6) & 3, wr = wg >> 1, wc = wg & 1;
    const int l15 = lane & 15, l4 = lane >> 4;
    char* base = ls + g * 32768;          // per group: buf0 {A,B} | buf1 {A,B}
    const ushort* Ap = A + (size_t)m0 * 2048 + (size_t)g * 1024;
    const ushort* Bp = BT + (size_t)c0 * 2048 + (size_t)g * 1024;

    f32x4 z = {0.f, 0.f, 0.f, 0.f};
    f32x4 acc[2][2];
    acc[0][0] = z; acc[0][1] = z; acc[1][0] = z; acc[1][1] = z;

    stage64x64(Ap, 2048, base, t256);
    stage64x64(Bp, 2048, base + 8192, t256);
    for (int ts = 0; ts < 16; ++ts) {
        char* cur = base + (ts & 1) * 16384;
        if (ts < 15) {
            char* nxt = base + ((ts + 1) & 1) * 16384;
            stage64x64(Ap + (ts + 1) * 64, 2048, nxt, t256);
            stage64x64(Bp + (ts + 1) * 64, 2048, nxt + 8192, t256);
            vmwait4();                    // my 4 loads for cur are done
        } else {
            vmwait0();
        }
        blockbar();                       // everyone's cur loads done
#pragma unroll
        for (int s = 0; s < 2; ++s) {
            const int kb = s * 64 + l4 * 16;
            bf16x8 aF[2], bF[2];
#pragma unroll
            for (int f = 0; f < 2; ++f) {
                aF[f] = fragld(cur, wr * 32 + f * 16 + l15, kb);
                bF[f] = fragld(cur + 8192, wc * 32 + f * 16 + l15, kb);
            }
#pragma unroll
            for (int i = 0; i < 2; ++i)
#pragma unroll
                for (int j = 0; j < 2; ++j)
                    acc[i][j] = __builtin_amdgcn_mfma_f32_16x16x32_bf16(aF[i], bF[j], acc[i][j], 0, 0, 0);
        }
        lgwait0();                        // my ds_reads of cur done
        blockbar();                       // everyone done reading cur -> reusable
    }

    // cross-group reduce + epilogue (post-pipeline; plain syncthreads fine)
    float* red = (float*)ls;              // 64*65*4 = 16640 B
    ushort* tileo = (ushort*)(ls + 17408);
    if (g == 0) {
#pragma unroll
        for (int i = 0; i < 2; ++i)
#pragma unroll
            for (int j = 0; j < 2; ++j) {
                const int lrb = wr * 32 + i * 16 + l4 * 4;
                const int lc = wc * 32 + j * 16 + l15;
#pragma unroll
                for (int r = 0; r < 4; ++r) red[(lrb + r) * 65 + lc] = acc[i][j][r];
            }
    }
    __syncthreads();
    if (g == 1) {
#pragma unroll
        for (int i = 0; i < 2; ++i)
#pragma unroll
            for (int j = 0; j < 2; ++j) {
                const int lrb = wr * 32 + i * 16 + l4 * 4;
                const int lc = wc * 32 + j * 16 + l15;
                float vv[4];
#pragma unroll
                for (int r = 0; r < 4; ++r) vv[r] = red[(lrb + r) * 65 + lc] + acc[i][j][r];
                if (MODE == 1) {
                    ushort4 ci = *(const ushort4*)&CinT[(size_t)(c0 + lc) * 2048 + m0 + lrb];
                    vv[0] = 2.f * vv[0] - bf16_to_f32(ci.x);
                    vv[1] = 2.f * vv[1] - bf16_to_f32(ci.y);
                    vv[2] = 2.f * vv[2] - bf16_to_f32(ci.z);
                    vv[3] = 2.f * vv[3] - bf16_to_f32(ci.w);
                }
                ushort4 p;
                p.x = f32_to_bf16(vv[0]); p.y = f32_to_bf16(vv[1]);
                p.z = f32_to_bf16(vv[2]); p.w = f32_to_bf16(vv[3]);
                *(ushort4*)&YT[(size_t)(c0 + lc) * 2048 + m0 + lrb] = p;
                tileo[(lrb + 0) * 64 + lc] = p.x;
                tileo[(lrb + 1) * 64 + lc] = p.y;
                tileo[(lrb + 2) * 64 + lc] = p.z;
                tileo[(lrb + 3) * 64 + lc] = p.w;
            }
    }
    __syncthreads();
    {
        int row = t >> 3, ch = t & 7;
        *(uint4*)&Yo[(size_t)(m0 + row) * 512 + c0 + ch * 8] = *(uint4*)&tileo[row * 64 + ch * 8];
    }
}

// =================== gemm3 body: WaX 2-product (Wa1@X1 + Wa1@X2), in-block K-split ===================
__device__ __forceinline__ void gemm3_body(int bx, const ushort* __restrict__ A1,
        const ushort* __restrict__ B1, const ushort* __restrict__ B2,
        float* __restrict__ WaXT, char* ls) {
    const int t = threadIdx.x;
    const int g = t >> 8, t256 = t & 255;
    const int m0 = (bx & 31) * 64, c0 = (bx >> 5) * 64;
    const int lane = t & 63;
    const int wg = (t >> 6) & 3, wr = wg >> 1, wc = wg & 1;
    const int l15 = lane & 15, l4 = lane >> 4;
    char* base = ls + g * 24576;          // per group: A1, B1, B2 x 8KB
    const size_t kbase = (size_t)g * 1024;

    f32x4 z = {0.f, 0.f, 0.f, 0.f};
    f32x4 acc[2][2];
    acc[0][0] = z; acc[0][1] = z; acc[1][0] = z; acc[1][1] = z;

    for (int k0 = 0; k0 < 1024; k0 += 64) {
        stage64x64(A1 + (size_t)m0 * 2048 + kbase + k0, 2048, base + 0 * 8192, t256);
        stage64x64(B1 + (size_t)c0 * 2048 + kbase + k0, 2048, base + 1 * 8192, t256);
        stage64x64(B2 + (size_t)c0 * 2048 + kbase + k0, 2048, base + 2 * 8192, t256);
        __syncthreads();
#pragma unroll
        for (int s = 0; s < 2; ++s) {
            const int kb = s * 64 + l4 * 16;
            bf16x8 a1F[2], b1F[2], b2F[2];
#pragma unroll
            for (int f = 0; f < 2; ++f) {
                const int ar = wr * 32 + f * 16 + l15;
                const int br = wc * 32 + f * 16 + l15;
                a1F[f] = fragld(base + 0 * 8192, ar, kb);
                b1F[f] = fragld(base + 1 * 8192, br, kb);
                b2F[f] = fragld(base + 2 * 8192, br, kb);
            }
#pragma unroll
            for (int i = 0; i < 2; ++i)
#pragma unroll
                for (int j = 0; j < 2; ++j) {
                    f32x4 a = acc[i][j];
                    a = __builtin_amdgcn_mfma_f32_16x16x32_bf16(a1F[i], b1F[j], a, 0, 0, 0);
                    a = __builtin_amdgcn_mfma_f32_16x16x32_bf16(a1F[i], b2F[j], a, 0, 0, 0);
                    acc[i][j] = a;
                }
        }
        __syncthreads();
    }

    float* red = (float*)ls;
    if (g == 0) {
#pragma unroll
        for (int i = 0; i < 2; ++i)
#pragma unroll
            for (int j = 0; j < 2; ++j) {
                const int lrb = wr * 32 + i * 16 + l4 * 4;
                const int lc = wc * 32 + j * 16 + l15;
#pragma unroll
                for (int r = 0; r < 4; ++r) red[(lrb + r) * 65 + lc] = acc[i][j][r];
            }
    }
    __syncthreads();
    if (g == 1) {
#pragma unroll
        for (int i = 0; i < 2; ++i)
#pragma unroll
            for (int j = 0; j < 2; ++j) {
                const int lrb = wr * 32 + i * 16 + l4 * 4;
                const int lc = wc * 32 + j * 16 + l15;
                f32x4 v;
#pragma unroll
                for (int r = 0; r < 4; ++r) v[r] = red[(lrb + r) * 65 + lc] + acc[i][j][r];
                *(f32x4*)&WaXT[(size_t)(c0 + lc) * 2048 + m0 + lrb] = v;
            }
    }
}

// =================== gram body: 256 blocks (8 b x 32 chunks of 64 n), 512 thr ===================
__device__ __forceinline__ void gram_body(int bx, const float* __restrict__ WaXT,
        const ushort* __restrict__ XT1, const ushort* __restrict__ XT2,
        float* __restrict__ Gpart, char* lsraw) {
    const int b = bx & 7, chunk = bx >> 3;
    float (*Lw)[68] = (float(*)[68])lsraw;
    float (*Rx)[68] = (float(*)[68])(lsraw + 64 * 68 * 4);
    const int t = threadIdx.x;
    const int n0 = chunk * 64;
    {   // all 512 threads load 64x64 of Lw and Rx (8 f32 each)
        const int r = t >> 3, q = (t & 7) * 8;
        size_t a = (size_t)(b * 64 + r) * 2048 + n0 + q;
        *(float4*)&Lw[r][q]     = *(const float4*)&WaXT[a];
        *(float4*)&Lw[r][q + 4] = *(const float4*)&WaXT[a + 4];
#pragma unroll
        for (int h = 0; h < 2; ++h) {
            ushort4 h1 = *(const ushort4*)&XT1[a + h * 4];
            ushort4 h2 = *(const ushort4*)&XT2[a + h * 4];
            Rx[r][q + h * 4 + 0] = bf16_to_f32(h1.x) + bf16_to_f32(h2.x);
            Rx[r][q + h * 4 + 1] = bf16_to_f32(h1.y) + bf16_to_f32(h2.y);
            Rx[r][q + h * 4 + 2] = bf16_to_f32(h1.z) + bf16_to_f32(h2.z);
            Rx[r][q + h * 4 + 3] = bf16_to_f32(h1.w) + bf16_to_f32(h2.w);
        }
    }
    __syncthreads();
    if (t < 256) {
        const int tx = t & 15, ty = t >> 4;
        float acc[4][4] = {{0.f,0.f,0.f,0.f},{0.f,0.f,0.f,0.f},{0.f,0.f,0.f,0.f},{0.f,0.f,0.f,0.f}};
        for (int n = 0; n < 64; ++n) {
            float a[4], bb[4];
#pragma unroll
            for (int i = 0; i < 4; ++i) { a[i] = Lw[ty * 4 + i][n]; bb[i] = Rx[tx * 4 + i][n]; }
#pragma unroll
            for (int i = 0; i < 4; ++i)
#pragma unroll
                for (int j = 0; j < 4; ++j) acc[i][j] = fmaf(a[i], bb[j], acc[i][j]);
        }
        float* gp = Gpart + (size_t)(chunk * 8 + b) * 4096;
#pragma unroll
        for (int i = 0; i < 4; ++i)
            *(float4*)&gp[(ty * 4 + i) * 64 + tx * 4] =
                make_float4(acc[i][0], acc[i][1], acc[i][2], acc[i][3]);
    }
}

// =================== cheb body: per-batch 64x64 Chebyshev; 512 thr, t<256 compute ===================
__device__ __forceinline__ void cheb_body(int b, const float* __restrict__ Gpart,
        const float* __restrict__ Thd, ushort* __restrict__ DT1, ushort* __restrict__ DT2,
        char* lsraw) {
    float (*Gs)[68]  = (float(*)[68])lsraw;
    float (*C2s)[68] = (float(*)[68])(lsraw + 17408);
    float (*C3s)[68] = (float(*)[68])(lsraw + 34816);
    const int t = threadIdx.x;
    for (int i = t; i < 4096; i += 512) {      // fold 32-chunk reduce in
        float s = 0.f;
#pragma unroll
        for (int c = 0; c < 32; ++c) s += Gpart[((size_t)c * 8 + b) * 4096 + i];
        Gs[i >> 6][i & 63] = s;
    }
    __syncthreads();
    const int tx = t & 15, ty = (t >> 4) & 15;
    const int r0 = ty * 4, c0 = tx * 4;
    const bool act = t < 256;

    if (act) {   // C2 = 2*G@G - I
        float p[4][4] = {{0,0,0,0},{0,0,0,0},{0,0,0,0},{0,0,0,0}};
        for (int k = 0; k < 64; ++k) {
            float ar[4] = {Gs[r0][k], Gs[r0+1][k], Gs[r0+2][k], Gs[r0+3][k]};
            float4 bv = *(const float4*)&Gs[k][c0];
            float br[4] = {bv.x, bv.y, bv.z, bv.w};
#pragma unroll
            for (int i = 0; i < 4; ++i)
#pragma unroll
                for (int j = 0; j < 4; ++j) p[i][j] = fmaf(ar[i], br[j], p[i][j]);
        }
#pragma unroll
        for (int i = 0; i < 4; ++i)
#pragma unroll
            for (int j = 0; j < 4; ++j)
                C2s[r0+i][c0+j] = 2.f * p[i][j] - ((r0+i) == (c0+j) ? 1.f : 0.f);
    }
    __syncthreads();
    if (act) {   // C3 = 2*G@C2 - G
        float q[4][4] = {{0,0,0,0},{0,0,0,0},{0,0,0,0},{0,0,0,0}};
        for (int k = 0; k < 64; ++k) {
            float ar[4] = {Gs[r0][k], Gs[r0+1][k], Gs[r0+2][k], Gs[r0+3][k]};
            float4 bv = *(const float4*)&C2s[k][c0];
            float br[4] = {bv.x, bv.y, bv.z, bv.w};
#pragma unroll
            for (int i = 0; i < 4; ++i)
#pragma unroll
                for (int j = 0; j < 4; ++j) q[i][j] = fmaf(ar[i], br[j], q[i][j]);
        }
#pragma unroll
        for (int i = 0; i < 4; ++i)
#pragma unroll
            for (int j = 0; j < 4; ++j)
                C3s[r0+i][c0+j] = 2.f * q[i][j] - Gs[r0+i][c0+j];
    }
    __syncthreads();
    float d[4][4];
    if (act) {   // D = Thd0 + G@Thd1 + C2@Thd2 + C3@Thd3
#pragma unroll
        for (int i = 0; i < 4; ++i) {
            float4 t0 = *(const float4*)&Thd[(r0+i) * 64 + c0];
            d[i][0] = t0.x; d[i][1] = t0.y; d[i][2] = t0.z; d[i][3] = t0.w;
        }
        for (int k = 0; k < 64; ++k) {
            float4 t1 = *(const float4*)&Thd[4096 + k * 64 + c0];
            float4 t2 = *(const float4*)&Thd[8192 + k * 64 + c0];
            float4 t3 = *(const float4*)&Thd[12288 + k * 64 + c0];
            float a1[4] = {Gs[r0][k], Gs[r0+1][k], Gs[r0+2][k], Gs[r0+3][k]};
            float a2[4] = {C2s[r0][k], C2s[r0+1][k], C2s[r0+2][k], C2s[r0+3][k]};
            float a3[4] = {C3s[r0][k], C3s[r0+1][k], C3s[r0+2][k], C3s[r0+3][k]};
            float b1[4] = {t1.x, t1.y, t1.z, t1.w};
            float b2[4] = {t2.x, t2.y, t2.z, t2.w};
            float b3[4] = {t3.x, t3.y, t3.z, t3.w};
#pragma unroll
            for (int i = 0; i < 4; ++i)
#pragma unroll
                for (int j = 0; j < 4; ++j) {
                    d[i][j] = fmaf(a1[i], b1[j], d[i][j]);
                    d[i][j] = fmaf(a2[i], b2[j], d[i][j]);
                    d[i][j] = fmaf(a3[i], b3[j], d[i][j]);
                }
        }
    }
    __syncthreads();
    if (act) {
#pragma unroll
        for (int i = 0; i < 4; ++i)
#pragma unroll
            for (int j = 0; j < 4; ++j) Gs[r0 + i][c0 + j] = d[i][j];
    }
    __syncthreads();
    for (int it = 0; it < 8; ++it) {
        int idx = it * 512 + t;              // o*64 + i (transposed emit)
        int o = idx >> 6, ii = idx & 63;
        ushort h1, h2;
        split2(Gs[ii][o], h1, h2);
        DT1[b * 4096 + idx] = h1;
        DT2[b * 4096 + idx] = h2;
    }
}

// =================== mega kernels: block-role fusion for co-residency ===================
__global__ __launch_bounds__(512, 4) void mega1(const ushort* __restrict__ Wa1,
        const ushort* __restrict__ XT1, const ushort* __restrict__ XT2,
        float* __restrict__ WaXT,
        const ushort* __restrict__ Ws16, ushort* __restrict__ Y1T, ushort* __restrict__ Y1o) {
    __shared__ __align__(16) char ls[65536];
    const int bx = blockIdx.x;
    if (bx < 256) gemm3_body(bx, Wa1, XT1, XT2, WaXT, ls);
    else          gemm_s_body<0>(bx - 256, Ws16, XT1, nullptr, Y1T, Y1o, ls);
}

__global__ __launch_bounds__(512, 4) void mega2(const ushort* __restrict__ Ws16,
        const ushort* __restrict__ Y1T, const ushort* __restrict__ XT1,
        ushort* __restrict__ Y2T, ushort* __restrict__ Y2o,
        const float* __restrict__ WaXT, const ushort* __restrict__ XT2,
        float* __restrict__ Gpart) {
    __shared__ __align__(16) char ls[65536];
    const int bx = blockIdx.x;
    if (bx < 256) gemm_s_body<1>(bx, Ws16, Y1T, XT1, Y2T, Y2o, ls);
    else          gram_body(bx - 256, WaXT, XT1, XT2, Gpart, ls);
}

__global__ __launch_bounds__(512, 4) void mega3(const ushort* __restrict__ Ws16,
        const ushort* __restrict__ Y2T, const ushort* __restrict__ Y1T,
        ushort* __restrict__ Y3T, ushort* __restrict__ Y3o,
        const float* __restrict__ Gpart, const float* __restrict__ Thd,
        ushort* __restrict__ DT1, ushort* __restrict__ DT2) {
    __shared__ __align__(16) char ls[65536];
    const int bx = blockIdx.x;
    if (bx < 256) gemm_s_body<1>(bx, Ws16, Y2T, Y1T, Y3T, Y3o, ls);
    else          cheb_body(bx - 256, Gpart, Thd, DT1, DT2, ls);
}

// =================== fused epilogue (R4-proven) ===================
__global__ __launch_bounds__(256) void ep_fused(const ushort* __restrict__ ThsT,
                                                const ushort* __restrict__ DT1, const ushort* __restrict__ DT2,
                                                const ushort* __restrict__ X1o, const ushort* __restrict__ X2o,
                                                const ushort* __restrict__ Y1o, const ushort* __restrict__ Y2o,
                                                const ushort* __restrict__ Y3o,
                                                float* __restrict__ out) {
    __shared__ __align__(16) char ls[65536];
    const int b = blockIdx.y, n0 = blockIdx.x * 64;
    const int t = threadIdx.x, lane = t & 63, w = t >> 6, wr = w >> 1, wc = w & 1;
    const int l15 = lane & 15, l4 = lane >> 4;
    stage64x64(X1o + (size_t)n0 * 512 + b * 64, 512, ls + 0 * 8192, t);
    stage64x64(Y1o + (size_t)n0 * 512 + b * 64, 512, ls + 1 * 8192, t);
    stage64x64(Y2o + (size_t)n0 * 512 + b * 64, 512, ls + 2 * 8192, t);
    stage64x64(Y3o + (size_t)n0 * 512 + b * 64, 512, ls + 3 * 8192, t);
    stage64x64(ThsT + 0 * 4096, 64, ls + 4 * 8192, t);
    stage64x64(ThsT + 1 * 4096, 64, ls + 5 * 8192, t);
    stage64x64(ThsT + 2 * 4096, 64, ls + 6 * 8192, t);
    stage64x64(ThsT + 3 * 4096, 64, ls + 7 * 8192, t);
    __syncthreads();
    f32x4 z = {0.f, 0.f, 0.f, 0.f};
    f32x4 as[2][2], ad[2][2];
    as[0][0] = z; as[0][1] = z; as[1][0] = z; as[1][1] = z;
    ad[0][0] = z; ad[0][1] = z; ad[1][0] = z; ad[1][1] = z;
#pragma unroll
    for (int s = 0; s < 2; ++s) {
        const int kb = s * 64 + l4 * 16;
#pragma unroll
        for (int p = 0; p < 4; ++p) {
            bf16x8 aF[2], bF[2];
#pragma unroll
            for (int f = 0; f < 2; ++f) {
                aF[f] = fragld(ls + (4 + p) * 8192, wr * 32 + f * 16 + l15, kb);
                bF[f] = fragld(ls + p * 8192, wc * 32 + f * 16 + l15, kb);
            }
#pragma unroll
            for (int i = 0; i < 2; ++i)
#pragma unroll
                for (int j = 0; j < 2; ++j)
                    as[i][j] = __builtin_amdgcn_mfma_f32_16x16x32_bf16(aF[i], bF[j], as[i][j], 0, 0, 0);
        }
    }
    __syncthreads();
    stage64x64(DT1 + b * 4096, 64, ls + 1 * 8192, t);
    stage64x64(DT2 + b * 4096, 64, ls + 2 * 8192, t);
    stage64x64(X2o + (size_t)n0 * 512 + b * 64, 512, ls + 3 * 8192, t);
    __syncthreads();
#pragma unroll
    for (int s = 0; s < 2; ++s) {
        const int kb = s * 64 + l4 * 16;
        bf16x8 a1[2], a2[2], b0[2], b3[2];
#pragma unroll
        for (int f = 0; f < 2; ++f) {
            a1[f] = fragld(ls + 1 * 8192, wr * 32 + f * 16 + l15, kb);
            a2[f] = fragld(ls + 2 * 8192, wr * 32 + f * 16 + l15, kb);
            b0[f] = fragld(ls + 0 * 8192, wc * 32 + f * 16 + l15, kb);
            b3[f] = fragld(ls + 3 * 8192, wc * 32 + f * 16 + l15, kb);
        }
#pragma unroll
        for (int i = 0; i < 2; ++i)
#pragma unroll
            for (int j = 0; j < 2; ++j) {
                f32x4 a = ad[i][j];
                a = __builtin_amdgcn_mfma_f32_16x16x32_bf16(a1[i], b0[j], a, 0, 0, 0);
                a = __builtin_amdgcn_mfma_f32_16x16x32_bf16(a1[i], b3[j], a, 0, 0, 0);
                a = __builtin_amdgcn_mfma_f32_16x16x32_bf16(a2[i], b0[j], a, 0, 0, 0);
                ad[i][j] = a;
            }
    }
#pragma unroll
    for (int i = 0; i < 2; ++i)
#pragma unroll
        for (int j = 0; j < 2; ++j) {
            const int ob = wr * 32 + i * 16 + l4 * 4;
            const int nn = wc * 32 + j * 16 + l15;
            float4 o4;
            o4.x = fmaxf(as[i][j][0], 0.f) + fmaxf(ad[i][j][0], 0.f);
            o4.y = fmaxf(as[i][j][1], 0.f) + fmaxf(ad[i][j][1], 0.f);
            o4.z = fmaxf(as[i][j][2], 0.f) + fmaxf(ad[i][j][2], 0.f);
            o4.w = fmaxf(as[i][j][3], 0.f) + fmaxf(ad[i][j][3], 0.f);
            *(float4*)&out[((size_t)b * 2048 + n0 + nn) * 64 + ob] = o4;
        }
}

extern "C" void kernel_launch(void* const* d_in, const int* in_sizes, int n_in,
                              void* d_out, int out_size, void* d_ws, size_t ws_size,
                              hipStream_t stream) {
    (void)in_sizes; (void)n_in; (void)out_size;
    const float* X   = (const float*)d_in[0];
    const float* Ws  = (const float*)d_in[1];
    const float* Wa  = (const float*)d_in[2];
    const float* Ths = (const float*)d_in[3];
    const float* Thd = (const float*)d_in[4];

    char* p = (char*)d_ws;
    auto alloc = [&](size_t bytes) { char* r = p; p += (bytes + 255) & ~(size_t)255; return r; };
    ushort* XT1 = (ushort*)alloc(512ull * 2048 * 2);
    ushort* XT2 = (ushort*)alloc(512ull * 2048 * 2);
    ushort* X1o = (ushort*)alloc(2048ull * 512 * 2);
    ushort* X2o = (ushort*)alloc(2048ull * 512 * 2);
    ushort* Ws16 = (ushort*)alloc(2048ull * 2048 * 2);
    ushort* Wa1 = (ushort*)alloc(2048ull * 2048 * 2);
    ushort* Y1T = (ushort*)alloc(512ull * 2048 * 2);
    ushort* Y2T = (ushort*)alloc(512ull * 2048 * 2);
    ushort* Y3T = (ushort*)alloc(512ull * 2048 * 2);
    ushort* Y1o = (ushort*)alloc(2048ull * 512 * 2);
    ushort* Y2o = (ushort*)alloc(2048ull * 512 * 2);
    ushort* Y3o = (ushort*)alloc(2048ull * 512 * 2);
    float*  Gpart = (float*)alloc(32ull * 8 * 4096 * 4);
    ushort* DT1 = (ushort*)alloc(8ull * 4096 * 2);
    ushort* DT2 = (ushort*)alloc(8ull * 4096 * 2);
    ushort* ThsT = (ushort*)alloc(4ull * 4096 * 2);
    if ((size_t)(p - (char*)d_ws) > ws_size) return;   // visible failure if ws too small
    float* WaXT = (float*)d_out;                       // 4MB scratch, overwritten by ep_fused later

    prep_all<<<4416, 256, 0, stream>>>(X, XT1, XT2, X1o, X2o, Ws, Ws16, Wa, Wa1, Ths, ThsT);
    mega1<<<512, 512, 0, stream>>>(Wa1, XT1, XT2, WaXT, Ws16, Y1T, Y1o);
    mega2<<<512, 512, 0, stream>>>(Ws16, Y1T, XT1, Y2T, Y2o, WaXT, XT2, Gpart);
    mega3<<<264, 512, 0, stream>>>(Ws16, Y2T, Y1T, Y3T, Y3o, Gpart, Thd, DT1, DT2);
    ep_fused<<<dim3(32, 8), 256, 0, stream>>>(ThsT, DT1, DT2, X1o, X2o, Y1o, Y2o, Y3o, (float*)d_out);
}